// Round 1
// baseline (1139.022 us; speedup 1.0000x reference)
//
#include <hip/hip_runtime.h>

#define NB  32
#define NC  256
#define NCQ 64
#define WHT 4096                  // 64*64 spatial
#define DQK ((size_t)NCQ * WHT)   // 262144
#define MV  ((size_t)NC * WHT)    // 1048576

// ---------------------------------------------------------------------------
// K1: fused q/k/v 1x1-conv projections.
// grid (16 spatial tiles of 256, 32 batches, 2 halves), 256 threads.
// Thread t owns spatial position s0+t. Weights are read with wave-uniform
// indices -> compiler emits s_load into SGPRs; x reads are fully coalesced.
// z=0: v channels 0..127 + q(64).  z=1: v channels 128..255 + k(64).
// ---------------------------------------------------------------------------
__global__ __launch_bounds__(256)
void qkv_kernel(const float* __restrict__ x0, const float* __restrict__ x1,
                const float* __restrict__ Wq, const float* __restrict__ bq,
                const float* __restrict__ Wk, const float* __restrict__ bk,
                const float* __restrict__ Wv, const float* __restrict__ bv,
                float* __restrict__ q, float* __restrict__ k, float* __restrict__ v)
{
    const int t  = threadIdx.x;
    const int s0 = blockIdx.x * 256;
    const int b  = blockIdx.y;
    const int z  = blockIdx.z;

    const float* xb0 = x0 + (size_t)b * NC * WHT + s0 + t;

    // ---- v half: 4 groups of 32 output channels ----
    for (int cg = 0; cg < 4; ++cg) {
        const int cbase = z * 128 + cg * 32;
        float acc[32];
#pragma unroll
        for (int c = 0; c < 32; ++c) acc[c] = 0.f;
        for (int k8 = 0; k8 < NC; k8 += 8) {
            float xv[8];
#pragma unroll
            for (int u = 0; u < 8; ++u) xv[u] = xb0[(size_t)(k8 + u) * WHT];
#pragma unroll
            for (int c = 0; c < 32; ++c) {
                const float* wr = Wv + (size_t)(cbase + c) * NC + k8;
#pragma unroll
                for (int u = 0; u < 8; ++u) acc[c] = fmaf(wr[u], xv[u], acc[c]);
            }
        }
#pragma unroll
        for (int c = 0; c < 32; ++c)
            v[((size_t)b * NC + cbase + c) * WHT + s0 + t] = acc[c] + bv[cbase + c];
    }

    if (z == 0) {
        // ---- q: 64 channels from x0 ----
        for (int cg = 0; cg < 2; ++cg) {
            const int cbase = cg * 32;
            float acc[32];
#pragma unroll
            for (int c = 0; c < 32; ++c) acc[c] = 0.f;
            for (int k8 = 0; k8 < NC; k8 += 8) {
                float xv[8];
#pragma unroll
                for (int u = 0; u < 8; ++u) xv[u] = xb0[(size_t)(k8 + u) * WHT];
#pragma unroll
                for (int c = 0; c < 32; ++c) {
                    const float* wr = Wq + (size_t)(cbase + c) * NC + k8;
#pragma unroll
                    for (int u = 0; u < 8; ++u) acc[c] = fmaf(wr[u], xv[u], acc[c]);
                }
            }
#pragma unroll
            for (int c = 0; c < 32; ++c)
                q[((size_t)b * NCQ + cbase + c) * WHT + s0 + t] = acc[c] + bq[cbase + c];
        }
    } else {
        // ---- k: 64 channels from x1 ----
        const float* xb1 = x1 + (size_t)b * NC * WHT + s0 + t;
        for (int cg = 0; cg < 2; ++cg) {
            const int cbase = cg * 32;
            float acc[32];
#pragma unroll
            for (int c = 0; c < 32; ++c) acc[c] = 0.f;
            for (int k8 = 0; k8 < NC; k8 += 8) {
                float xv[8];
#pragma unroll
                for (int u = 0; u < 8; ++u) xv[u] = xb1[(size_t)(k8 + u) * WHT];
#pragma unroll
                for (int c = 0; c < 32; ++c) {
                    const float* wr = Wk + (size_t)(cbase + c) * NC + k8;
#pragma unroll
                    for (int u = 0; u < 8; ++u) acc[c] = fmaf(wr[u], xv[u], acc[c]);
                }
            }
#pragma unroll
            for (int c = 0; c < 32; ++c)
                k[((size_t)b * NCQ + cbase + c) * WHT + s0 + t] = acc[c] + bk[cbase + c];
        }
    }
}

// ---------------------------------------------------------------------------
// K2: energy[i,j] = sum_d k[i,d]*q[j,d]  (32x32, K=262144)
// grid (1024 d-chunks of 256, 2 i-halves, 2 j-halves), 256 threads.
// Transposed padded LDS tiles; fp32 atomicAdd of per-chunk partials.
// ---------------------------------------------------------------------------
__global__ __launch_bounds__(256)
void energy_kernel(const float* __restrict__ q, const float* __restrict__ k,
                   float* __restrict__ energy)
{
    __shared__ float kt[256][17];
    __shared__ float qt[256][17];

    const int t  = threadIdx.x;
    const int d0 = blockIdx.x * 256;
    const int ih = blockIdx.y;   // i in [ih*16, ih*16+16)
    const int jh = blockIdx.z;

    for (int r = 0; r < 16; ++r) {
        kt[t][r] = k[(size_t)(ih * 16 + r) * DQK + d0 + t];
        qt[t][r] = q[(size_t)(jh * 16 + r) * DQK + d0 + t];
    }
    __syncthreads();

    const int ii = t >> 4;
    const int jj = t & 15;
    float acc = 0.f;
#pragma unroll 4
    for (int d = 0; d < 256; ++d)
        acc = fmaf(kt[d][ii], qt[d][jj], acc);

    atomicAdd(&energy[(ih * 16 + ii) * 32 + jh * 16 + jj], acc);
}

// ---------------------------------------------------------------------------
// K2b: row softmax of energy [32x32]. 1 block, 1024 threads.
// ---------------------------------------------------------------------------
__global__ __launch_bounds__(1024)
void softmax_kernel(const float* __restrict__ energy,
                    float* __restrict__ att, float* __restrict__ att_out)
{
    const int t = threadIdx.x;
    const int i = t >> 5;
    const int j = t & 31;
    float e = energy[i * 32 + j];
    float m = e;
#pragma unroll
    for (int o = 16; o; o >>= 1) m = fmaxf(m, __shfl_xor(m, o, 32));
    float ex = __expf(e - m);
    float s = ex;
#pragma unroll
    for (int o = 16; o; o >>= 1) s += __shfl_xor(s, o, 32);
    float a = ex / s;
    att[i * 32 + j] = a;
    att_out[i * 32 + j] = a;
}

// ---------------------------------------------------------------------------
// K3: out[i,m] = gamma * sum_j A[i,j]*v[j,m] + x1[i,m]
// grid 4096 m-tiles of 256, 256 threads. v column in 32 registers,
// A via wave-uniform scalar loads. Fully coalesced.
// ---------------------------------------------------------------------------
__global__ __launch_bounds__(256)
void out_kernel(const float* __restrict__ v, const float* __restrict__ att,
                const float* __restrict__ x1, const float* __restrict__ gamma,
                float* __restrict__ out)
{
    const int t = threadIdx.x;
    const size_t m0 = (size_t)blockIdx.x * 256;

    float vv[32];
#pragma unroll
    for (int j = 0; j < 32; ++j)
        vv[j] = v[(size_t)j * MV + m0 + t];

    const float g = gamma[0];
    for (int i = 0; i < 32; ++i) {
        float acc = 0.f;
#pragma unroll
        for (int j = 0; j < 32; ++j)
            acc = fmaf(att[i * 32 + j], vv[j], acc);
        out[(size_t)i * MV + m0 + t] = g * acc + x1[(size_t)i * MV + m0 + t];
    }
}

// ---------------------------------------------------------------------------
extern "C" void kernel_launch(void* const* d_in, const int* in_sizes, int n_in,
                              void* d_out, int out_size, void* d_ws, size_t ws_size,
                              hipStream_t stream)
{
    const float* x0    = (const float*)d_in[0];
    const float* x1    = (const float*)d_in[1];
    const float* Wq    = (const float*)d_in[2];
    const float* bq    = (const float*)d_in[3];
    const float* Wk    = (const float*)d_in[4];
    const float* bk    = (const float*)d_in[5];
    const float* Wv    = (const float*)d_in[6];
    const float* bv    = (const float*)d_in[7];
    const float* gamma = (const float*)d_in[8];

    float* ws     = (float*)d_ws;
    float* q      = ws;                                  //  8,388,608 f
    float* k      = q + (size_t)NB * NCQ * WHT;          //  8,388,608 f
    float* v      = k + (size_t)NB * NCQ * WHT;          // 33,554,432 f
    float* energy = v + (size_t)NB * NC * WHT;           //      1,024 f
    float* att    = energy + 1024;                       //      1,024 f

    float* out     = (float*)d_out;
    float* att_out = out + (size_t)NB * NC * WHT;

    hipMemsetAsync(energy, 0, 1024 * sizeof(float), stream);

    qkv_kernel<<<dim3(16, 32, 2), 256, 0, stream>>>(x0, x1, Wq, bq, Wk, bk, Wv, bv, q, k, v);
    energy_kernel<<<dim3(1024, 2, 2), 256, 0, stream>>>(q, k, energy);
    softmax_kernel<<<1, 1024, 0, stream>>>(energy, att, att_out);
    out_kernel<<<4096, 256, 0, stream>>>(v, att, x1, gamma, out);
}

// Round 2
// 417.635 us; speedup vs baseline: 2.7273x; 2.7273x over previous
//
#include <hip/hip_runtime.h>

#define NB  32
#define NC  256
#define NCQ 64
#define WHT 4096                  // 64*64 spatial
#define DQK ((size_t)NCQ * WHT)   // 262144
#define MV  ((size_t)NC * WHT)    // 1048576

typedef __attribute__((ext_vector_type(8))) short short8;
typedef __attribute__((ext_vector_type(4))) float f32x4;

__device__ __forceinline__ unsigned short bf16_rne(float f) {
    union { float f; unsigned u; } v; v.f = f;
    unsigned r = (v.u + 0x7fffu + ((v.u >> 16) & 1u)) >> 16;
    return (unsigned short)r;
}
__device__ __forceinline__ float bf16_f(unsigned short h) {
    union { unsigned u; float f; } v; v.u = ((unsigned)h) << 16; return v.f;
}

// ---------------------------------------------------------------------------
// P: convert weights to bf16 hi (+lo for q/k split-precision path)
// ---------------------------------------------------------------------------
__global__ __launch_bounds__(256)
void prep_w(const float* __restrict__ Wq, const float* __restrict__ Wk,
            const float* __restrict__ Wv,
            unsigned short* __restrict__ wv_hi,
            unsigned short* __restrict__ wq_hi, unsigned short* __restrict__ wq_lo,
            unsigned short* __restrict__ wk_hi, unsigned short* __restrict__ wk_lo)
{
    int i = blockIdx.x * 256 + threadIdx.x;
    if (i < 65536) {
        wv_hi[i] = bf16_rne(Wv[i]);
    } else if (i < 65536 + 16384) {
        int j = i - 65536;
        float f = Wq[j];
        unsigned short h = bf16_rne(f);
        wq_hi[j] = h; wq_lo[j] = bf16_rne(f - bf16_f(h));
    } else if (i < 65536 + 32768) {
        int j = i - 65536 - 16384;
        float f = Wk[j];
        unsigned short h = bf16_rne(f);
        wk_hi[j] = h; wk_lo[j] = bf16_rne(f - bf16_f(h));
    }
}

// ---------------------------------------------------------------------------
// K1: q/k/v projections via bf16 MFMA (split hi/lo for q,k; hi-only for v).
// Tile: BM=64 x BN=256, BK=32, 256 threads = 4 waves, each wave 64x64 out.
// M-tiles: 0..3 = v rows mt*64 (x0), 4 = q (x0), 5 = k (x1).
// XCD-bijective bid mapping co-locates the 6 M-tiles of one (b,nt) panel.
// ---------------------------------------------------------------------------
__global__ __launch_bounds__(256)
void qkv_mfma(const float* __restrict__ x0, const float* __restrict__ x1,
              const unsigned short* __restrict__ wv_hi,
              const unsigned short* __restrict__ wq_hi, const unsigned short* __restrict__ wq_lo,
              const unsigned short* __restrict__ wk_hi, const unsigned short* __restrict__ wk_lo,
              const float* __restrict__ bq, const float* __restrict__ bk,
              const float* __restrict__ bv,
              float* __restrict__ q, float* __restrict__ k, float* __restrict__ v)
{
    __shared__ short xs_hi[4][256][8];   // [kchunk][spatial][8 bf16]  16 KB
    __shared__ short xs_lo[4][256][8];   //                            16 KB
    __shared__ short wt_hi[4][64][8];    // [kchunk][row][8 bf16]       4 KB
    __shared__ short wt_lo[4][64][8];    //                             4 KB

    const int t   = threadIdx.x;
    const int bid = blockIdx.x;
    // bid -> (b, nt, mt) with all 6 mt of a (b,nt) group on one XCD (bid%8)
    const int xcd = bid & 7;
    const int sl  = bid >> 3;        // 0..383
    const int mt  = sl % 6;
    const int g   = (sl / 6) * 8 + xcd;  // 0..511
    const int nt  = g & 15;
    const int b   = g >> 4;

    const bool isV = (mt < 4);
    const bool isQ = (mt == 4);
    const int  s0  = nt * 256;

    const float* xsrc = ((mt == 5) ? x1 : x0) + (size_t)b * NC * WHT + s0;
    const unsigned short* whi = isV ? (wv_hi + mt * 64 * 256) : (isQ ? wq_hi : wk_hi);
    const unsigned short* wlo = isQ ? wq_lo : wk_lo;   // unused when isV

    const int wave = t >> 6;
    const int lane = t & 63;
    const int lh   = lane >> 4;   // k-chunk / row-group selector
    const int ll   = lane & 15;

    f32x4 acc[4][4];
#pragma unroll
    for (int m = 0; m < 4; ++m)
#pragma unroll
        for (int n = 0; n < 4; ++n) acc[m][n] = (f32x4){0.f, 0.f, 0.f, 0.f};

    const int wkc = t & 3;        // W staging: chunk
    const int wr  = t >> 2;       // W staging: row

    for (int kb = 0; kb < NC; kb += 32) {
        __syncthreads();
        // ---- stage x tile: thread t owns spatial position t ----
        {
            const float* xp = xsrc + t + (size_t)kb * WHT;
#pragma unroll
            for (int kc = 0; kc < 4; ++kc) {
                float xr[8];
#pragma unroll
                for (int e = 0; e < 8; ++e) xr[e] = xp[(size_t)(kc * 8 + e) * WHT];
                short8 h8, l8;
#pragma unroll
                for (int e = 0; e < 8; ++e) {
                    unsigned short h = bf16_rne(xr[e]);
                    h8[e] = (short)h;
                    l8[e] = (short)bf16_rne(xr[e] - bf16_f(h));
                }
                *(short8*)&xs_hi[kc][t][0] = h8;
                if (!isV) *(short8*)&xs_lo[kc][t][0] = l8;
            }
        }
        // ---- stage W tile ----
        {
            *(short8*)&wt_hi[wkc][wr][0] =
                *(const short8*)(whi + wr * NC + kb + wkc * 8);
            if (!isV)
                *(short8*)&wt_lo[wkc][wr][0] =
                    *(const short8*)(wlo + wr * NC + kb + wkc * 8);
        }
        __syncthreads();

        // ---- MFMA phase ----
        short8 a_hi[4], a_lo[4];
#pragma unroll
        for (int m = 0; m < 4; ++m) {
            a_hi[m] = *(const short8*)&wt_hi[lh][m * 16 + ll][0];
            if (!isV) a_lo[m] = *(const short8*)&wt_lo[lh][m * 16 + ll][0];
        }
#pragma unroll
        for (int n = 0; n < 4; ++n) {
            const int sc = wave * 64 + n * 16 + ll;
            short8 b_hi = *(const short8*)&xs_hi[lh][sc][0];
            if (isV) {
#pragma unroll
                for (int m = 0; m < 4; ++m)
                    acc[m][n] = __builtin_amdgcn_mfma_f32_16x16x32_bf16(
                        a_hi[m], b_hi, acc[m][n], 0, 0, 0);
            } else {
                short8 b_lo = *(const short8*)&xs_lo[lh][sc][0];
#pragma unroll
                for (int m = 0; m < 4; ++m) {
                    acc[m][n] = __builtin_amdgcn_mfma_f32_16x16x32_bf16(
                        a_hi[m], b_hi, acc[m][n], 0, 0, 0);
                    acc[m][n] = __builtin_amdgcn_mfma_f32_16x16x32_bf16(
                        a_hi[m], b_lo, acc[m][n], 0, 0, 0);
                    acc[m][n] = __builtin_amdgcn_mfma_f32_16x16x32_bf16(
                        a_lo[m], b_hi, acc[m][n], 0, 0, 0);
                }
            }
        }
    }

    // ---- epilogue: add bias, store fp32 ----
    float* outp; const float* bias;
    if (isV)      { outp = v + ((size_t)b * NC + mt * 64) * WHT; bias = bv + mt * 64; }
    else if (isQ) { outp = q + (size_t)b * NCQ * WHT;            bias = bq; }
    else          { outp = k + (size_t)b * NCQ * WHT;            bias = bk; }

#pragma unroll
    for (int m = 0; m < 4; ++m) {
#pragma unroll
        for (int n = 0; n < 4; ++n) {
            const int col = s0 + wave * 64 + n * 16 + ll;
#pragma unroll
            for (int r = 0; r < 4; ++r) {
                const int row = m * 16 + 4 * lh + r;
                outp[(size_t)row * WHT + col] = acc[m][n][r] + bias[row];
            }
        }
    }
}

// ---------------------------------------------------------------------------
// K2: energy[i,j] = sum_d k[i,d]*q[j,d]  (32x32, K=262144) — unchanged
// ---------------------------------------------------------------------------
__global__ __launch_bounds__(256)
void energy_kernel(const float* __restrict__ q, const float* __restrict__ k,
                   float* __restrict__ energy)
{
    __shared__ float kt[256][17];
    __shared__ float qt[256][17];

    const int t  = threadIdx.x;
    const int d0 = blockIdx.x * 256;
    const int ih = blockIdx.y;
    const int jh = blockIdx.z;

    for (int r = 0; r < 16; ++r) {
        kt[t][r] = k[(size_t)(ih * 16 + r) * DQK + d0 + t];
        qt[t][r] = q[(size_t)(jh * 16 + r) * DQK + d0 + t];
    }
    __syncthreads();

    const int ii = t >> 4;
    const int jj = t & 15;
    float acc = 0.f;
#pragma unroll 4
    for (int d = 0; d < 256; ++d)
        acc = fmaf(kt[d][ii], qt[d][jj], acc);

    atomicAdd(&energy[(ih * 16 + ii) * 32 + jh * 16 + jj], acc);
}

// ---------------------------------------------------------------------------
// K2b: row softmax of energy [32x32]. 1 block, 1024 threads. — unchanged
// ---------------------------------------------------------------------------
__global__ __launch_bounds__(1024)
void softmax_kernel(const float* __restrict__ energy,
                    float* __restrict__ att, float* __restrict__ att_out)
{
    const int t = threadIdx.x;
    const int i = t >> 5;
    const int j = t & 31;
    float e = energy[i * 32 + j];
    float m = e;
#pragma unroll
    for (int o = 16; o; o >>= 1) m = fmaxf(m, __shfl_xor(m, o, 32));
    float ex = __expf(e - m);
    float s = ex;
#pragma unroll
    for (int o = 16; o; o >>= 1) s += __shfl_xor(s, o, 32);
    float a = ex / s;
    att[i * 32 + j] = a;
    att_out[i * 32 + j] = a;
}

// ---------------------------------------------------------------------------
// K3: out[i,m] = gamma * sum_j A[i,j]*v[j,m] + x1[i,m] — unchanged
// ---------------------------------------------------------------------------
__global__ __launch_bounds__(256)
void out_kernel(const float* __restrict__ v, const float* __restrict__ att,
                const float* __restrict__ x1, const float* __restrict__ gamma,
                float* __restrict__ out)
{
    const int t = threadIdx.x;
    const size_t m0 = (size_t)blockIdx.x * 256;

    float vv[32];
#pragma unroll
    for (int j = 0; j < 32; ++j)
        vv[j] = v[(size_t)j * MV + m0 + t];

    const float g = gamma[0];
    for (int i = 0; i < 32; ++i) {
        float acc = 0.f;
#pragma unroll
        for (int j = 0; j < 32; ++j)
            acc = fmaf(att[i * 32 + j], vv[j], acc);
        out[(size_t)i * MV + m0 + t] = g * acc + x1[(size_t)i * MV + m0 + t];
    }
}

// ---------------------------------------------------------------------------
extern "C" void kernel_launch(void* const* d_in, const int* in_sizes, int n_in,
                              void* d_out, int out_size, void* d_ws, size_t ws_size,
                              hipStream_t stream)
{
    const float* x0    = (const float*)d_in[0];
    const float* x1    = (const float*)d_in[1];
    const float* Wq    = (const float*)d_in[2];
    const float* bq    = (const float*)d_in[3];
    const float* Wk    = (const float*)d_in[4];
    const float* bk    = (const float*)d_in[5];
    const float* Wv    = (const float*)d_in[6];
    const float* bv    = (const float*)d_in[7];
    const float* gamma = (const float*)d_in[8];

    float* ws     = (float*)d_ws;
    float* q      = ws;                                  //  8,388,608 f
    float* k      = q + (size_t)NB * NCQ * WHT;          //  8,388,608 f
    float* v      = k + (size_t)NB * NCQ * WHT;          // 33,554,432 f
    float* energy = v + (size_t)NB * NC * WHT;           //      1,024 f
    float* att    = energy + 1024;                       //      1,024 f

    unsigned short* wv_hi = (unsigned short*)(att + 1024);   // 16B-aligned
    unsigned short* wq_hi = wv_hi + 65536;
    unsigned short* wq_lo = wq_hi + 16384;
    unsigned short* wk_hi = wq_lo + 16384;
    unsigned short* wk_lo = wk_hi + 16384;

    float* out     = (float*)d_out;
    float* att_out = out + (size_t)NB * NC * WHT;

    hipMemsetAsync(energy, 0, 1024 * sizeof(float), stream);

    prep_w<<<384, 256, 0, stream>>>(Wq, Wk, Wv, wv_hi, wq_hi, wq_lo, wk_hi, wk_lo);
    qkv_mfma<<<3072, 256, 0, stream>>>(x0, x1, wv_hi, wq_hi, wq_lo, wk_hi, wk_lo,
                                       bq, bk, bv, q, k, v);
    energy_kernel<<<dim3(1024, 2, 2), 256, 0, stream>>>(q, k, energy);
    softmax_kernel<<<1, 1024, 0, stream>>>(energy, att, att_out);
    out_kernel<<<4096, 256, 0, stream>>>(v, att, x1, gamma, out);
}

// Round 3
// 279.131 us; speedup vs baseline: 4.0806x; 1.4962x over previous
//
#include <hip/hip_runtime.h>

#define NB  32
#define NC  256
#define NCQ 64
#define WHT 4096                  // 64*64 spatial
#define DQK ((size_t)NCQ * WHT)   // 262144
#define MV  ((size_t)NC * WHT)    // 1048576

typedef __attribute__((ext_vector_type(8))) short short8;
typedef __attribute__((ext_vector_type(4))) float f32x4;
typedef __attribute__((ext_vector_type(2))) float f32x2;
typedef unsigned short ushort_t;

__device__ __forceinline__ ushort_t bf16_rne(float f) {
    union { float f; unsigned u; } v; v.f = f;
    unsigned r = (v.u + 0x7fffu + ((v.u >> 16) & 1u)) >> 16;
    return (ushort_t)r;
}
__device__ __forceinline__ float bf16_f(ushort_t h) {
    union { unsigned u; float f; } v; v.u = ((unsigned)h) << 16; return v.f;
}

// fragment-order offset within one 64x256 W tile (elements):
// value W[r][kk] lands at (kb=kk>>5)*2048 + lh*512 + m*128 + ll*8 + e
__device__ __forceinline__ int frag_off(int r, int kk) {
    return ((kk >> 5) * 16 + ((kk >> 3) & 3) * 4 + (r >> 4)) * 128
           + (r & 15) * 8 + (kk & 7);
}

// ---------------------------------------------------------------------------
// P: convert weights to bf16 hi (+lo for q/k), permuted to MFMA fragment order
// ---------------------------------------------------------------------------
__global__ __launch_bounds__(256)
void prep_w(const float* __restrict__ Wq, const float* __restrict__ Wk,
            const float* __restrict__ Wv,
            ushort_t* __restrict__ wv_hi,
            ushort_t* __restrict__ wq_hi, ushort_t* __restrict__ wq_lo,
            ushort_t* __restrict__ wk_hi, ushort_t* __restrict__ wk_lo)
{
    int i = blockIdx.x * 256 + threadIdx.x;
    if (i < 65536) {                       // Wv: 256 rows -> 4 tiles of 64
        int R = i >> 8, kk = i & 255;
        wv_hi[(R >> 6) * 16384 + frag_off(R & 63, kk)] = bf16_rne(Wv[i]);
    } else if (i < 81920) {                // Wq: 64 rows
        int j = i - 65536; int r = j >> 8, kk = j & 255;
        float f = Wq[j]; ushort_t h = bf16_rne(f);
        int o = frag_off(r, kk);
        wq_hi[o] = h; wq_lo[o] = bf16_rne(f - bf16_f(h));
    } else if (i < 98304) {                // Wk: 64 rows
        int j = i - 81920; int r = j >> 8, kk = j & 255;
        float f = Wk[j]; ushort_t h = bf16_rne(f);
        int o = frag_off(r, kk);
        wk_hi[o] = h; wk_lo[o] = bf16_rne(f - bf16_f(h));
    }
}

// ---------------------------------------------------------------------------
// K1: q/k/v projections, all-register MFMA (no LDS, no barriers).
// Per wave: 64 W-rows x 64 spatial. Block = 4 waves = 64 x 256 spatial.
// B-fragments loaded per-lane from x (dword, stride WHT); A-fragments from
// pre-permuted bf16 W (contiguous 16B). hi = trunc-top16 via v_perm; q/k use
// 3-pass hi/lo split MFMA; v is hi-only and stored bf16.
// ---------------------------------------------------------------------------
__global__ __launch_bounds__(256)
void qkv_mfma(const float* __restrict__ x0, const float* __restrict__ x1,
              const ushort_t* __restrict__ wv_hi,
              const ushort_t* __restrict__ wq_hi, const ushort_t* __restrict__ wq_lo,
              const ushort_t* __restrict__ wk_hi, const ushort_t* __restrict__ wk_lo,
              const float* __restrict__ bq, const float* __restrict__ bk,
              const float* __restrict__ bv,
              float* __restrict__ q, float* __restrict__ k,
              ushort_t* __restrict__ vbf)
{
    const int t   = threadIdx.x;
    const int bid = blockIdx.x;
    // bid -> (b, nt, mt): all 6 mt of one (b,nt) panel on one XCD (bid%8)
    const int xcd = bid & 7;
    const int sl  = bid >> 3;            // 0..383
    const int mt  = sl % 6;
    const int g   = (sl / 6) * 8 + xcd;  // 0..511
    const int nt  = g & 15;
    const int b   = g >> 4;

    const bool isV = (mt < 4);
    const bool isQ = (mt == 4);

    const int wave = t >> 6;
    const int lane = t & 63;
    const int lh   = lane >> 4;          // k-subchunk selector (0..3)
    const int ll   = lane & 15;

    const float* xsrc = ((mt == 5) ? x1 : x0) + (size_t)b * NC * WHT
                        + nt * 256 + wave * 64 + ll;
    const float* xw = xsrc + (size_t)lh * 8 * WHT;

    const ushort_t* whi = isV ? (wv_hi + mt * 16384) : (isQ ? wq_hi : wk_hi);
    const ushort_t* wlo = isQ ? wq_lo : wk_lo;
    const int abase = lh * 512 + ll * 8;

    f32x4 acc[4][4];
#pragma unroll
    for (int m = 0; m < 4; ++m)
#pragma unroll
        for (int n = 0; n < 4; ++n) acc[m][n] = (f32x4){0.f, 0.f, 0.f, 0.f};

    for (int kb = 0; kb < 8; ++kb) {
        // ---- A fragments (contiguous 16B, L2-hot) ----
        short8 a_hi[4], a_lo[4];
#pragma unroll
        for (int m = 0; m < 4; ++m)
            a_hi[m] = *(const short8*)(whi + kb * 2048 + abase + m * 128);
        if (!isV) {
#pragma unroll
            for (int m = 0; m < 4; ++m)
                a_lo[m] = *(const short8*)(wlo + kb * 2048 + abase + m * 128);
        }

        // ---- B: 32 per-lane dword loads ----
        const float* xk = xw + (size_t)kb * 32 * WHT;
        float xf[4][8];
#pragma unroll
        for (int n = 0; n < 4; ++n)
#pragma unroll
            for (int e = 0; e < 8; ++e)
                xf[n][e] = xk[(size_t)e * WHT + n * 16];

        // ---- hi = top16 truncation, packed 2-at-a-time via v_perm ----
        short8 bh[4];
#pragma unroll
        for (int n = 0; n < 4; ++n) {
            union { unsigned u[4]; short8 s; } pk;
#pragma unroll
            for (int p = 0; p < 4; ++p)
                pk.u[p] = __builtin_amdgcn_perm(
                    __float_as_uint(xf[n][2 * p + 1]),
                    __float_as_uint(xf[n][2 * p]), 0x07060302u);
            bh[n] = pk.s;
        }

        if (isV) {
#pragma unroll
            for (int n = 0; n < 4; ++n)
#pragma unroll
                for (int m = 0; m < 4; ++m)
                    acc[m][n] = __builtin_amdgcn_mfma_f32_16x16x32_bf16(
                        a_hi[m], bh[n], acc[m][n], 0, 0, 0);
        } else {
            short8 bl[4];
#pragma unroll
            for (int n = 0; n < 4; ++n) {
                float lo[8];
#pragma unroll
                for (int e = 0; e < 8; ++e) {
                    float hf = __uint_as_float(__float_as_uint(xf[n][e]) & 0xffff0000u);
                    lo[e] = xf[n][e] - hf;
                }
                union { unsigned u[4]; short8 s; } pk;
#pragma unroll
                for (int p = 0; p < 4; ++p)
                    pk.u[p] = __builtin_amdgcn_perm(
                        __float_as_uint(lo[2 * p + 1]),
                        __float_as_uint(lo[2 * p]), 0x07060302u);
                bl[n] = pk.s;
            }
#pragma unroll
            for (int n = 0; n < 4; ++n)
#pragma unroll
                for (int m = 0; m < 4; ++m) {
                    acc[m][n] = __builtin_amdgcn_mfma_f32_16x16x32_bf16(
                        a_hi[m], bh[n], acc[m][n], 0, 0, 0);
                    acc[m][n] = __builtin_amdgcn_mfma_f32_16x16x32_bf16(
                        a_hi[m], bl[n], acc[m][n], 0, 0, 0);
                    acc[m][n] = __builtin_amdgcn_mfma_f32_16x16x32_bf16(
                        a_lo[m], bh[n], acc[m][n], 0, 0, 0);
                }
        }
    }

    // ---- epilogue ----
    const int colbase = nt * 256 + wave * 64;
    if (isV) {
        ushort_t* outp = vbf + ((size_t)b * NC + mt * 64) * WHT + colbase;
        const float* bias = bv + mt * 64;
#pragma unroll
        for (int m = 0; m < 4; ++m)
#pragma unroll
            for (int n = 0; n < 4; ++n)
#pragma unroll
                for (int r = 0; r < 4; ++r) {
                    const int row = m * 16 + 4 * lh + r;
                    outp[(size_t)row * WHT + n * 16 + ll] =
                        bf16_rne(acc[m][n][r] + bias[row]);
                }
    } else {
        float* outp = (isQ ? q : k) + (size_t)b * NCQ * WHT + colbase;
        const float* bias = isQ ? bq : bk;
#pragma unroll
        for (int m = 0; m < 4; ++m)
#pragma unroll
            for (int n = 0; n < 4; ++n)
#pragma unroll
                for (int r = 0; r < 4; ++r) {
                    const int row = m * 16 + 4 * lh + r;
                    outp[(size_t)row * WHT + n * 16 + ll] =
                        acc[m][n][r] + bias[row];
                }
    }
}

// ---------------------------------------------------------------------------
// K2: energy[i,j] = sum_d k[i,d]*q[j,d]  (32x32, K=262144) — unchanged
// ---------------------------------------------------------------------------
__global__ __launch_bounds__(256)
void energy_kernel(const float* __restrict__ q, const float* __restrict__ k,
                   float* __restrict__ energy)
{
    __shared__ float kt[256][17];
    __shared__ float qt[256][17];

    const int t  = threadIdx.x;
    const int d0 = blockIdx.x * 256;
    const int ih = blockIdx.y;
    const int jh = blockIdx.z;

    for (int r = 0; r < 16; ++r) {
        kt[t][r] = k[(size_t)(ih * 16 + r) * DQK + d0 + t];
        qt[t][r] = q[(size_t)(jh * 16 + r) * DQK + d0 + t];
    }
    __syncthreads();

    const int ii = t >> 4;
    const int jj = t & 15;
    float acc = 0.f;
#pragma unroll 4
    for (int d = 0; d < 256; ++d)
        acc = fmaf(kt[d][ii], qt[d][jj], acc);

    atomicAdd(&energy[(ih * 16 + ii) * 32 + jh * 16 + jj], acc);
}

// ---------------------------------------------------------------------------
// K2b: row softmax of energy [32x32]. 1 block, 1024 threads. — unchanged
// ---------------------------------------------------------------------------
__global__ __launch_bounds__(1024)
void softmax_kernel(const float* __restrict__ energy,
                    float* __restrict__ att, float* __restrict__ att_out)
{
    const int t = threadIdx.x;
    const int i = t >> 5;
    const int j = t & 31;
    float e = energy[i * 32 + j];
    float m = e;
#pragma unroll
    for (int o = 16; o; o >>= 1) m = fmaxf(m, __shfl_xor(m, o, 32));
    float ex = __expf(e - m);
    float s = ex;
#pragma unroll
    for (int o = 16; o; o >>= 1) s += __shfl_xor(s, o, 32);
    float a = ex / s;
    att[i * 32 + j] = a;
    att_out[i * 32 + j] = a;
}

// ---------------------------------------------------------------------------
// K3: out[i,m] = gamma * sum_j A[i,j]*v[j,m] + x1[i,m]; v is bf16-packed.
// 2 spatial positions per thread (uint v loads, float2 x1/out).
// ---------------------------------------------------------------------------
__global__ __launch_bounds__(256)
void out_kernel(const ushort_t* __restrict__ vbf, const float* __restrict__ att,
                const float* __restrict__ x1, const float* __restrict__ gamma,
                float* __restrict__ out)
{
    const int t = threadIdx.x;
    const size_t m0 = (size_t)blockIdx.x * 512 + 2 * t;

    float v0[32], v1[32];
#pragma unroll
    for (int j = 0; j < 32; ++j) {
        unsigned u = *(const unsigned*)(vbf + (size_t)j * MV + m0);
        v0[j] = __uint_as_float(u << 16);
        v1[j] = __uint_as_float(u & 0xffff0000u);
    }

    const float g = gamma[0];
    for (int i = 0; i < 32; ++i) {
        float a0 = 0.f, a1 = 0.f;
#pragma unroll
        for (int j = 0; j < 32; ++j) {
            float w = att[i * 32 + j];
            a0 = fmaf(w, v0[j], a0);
            a1 = fmaf(w, v1[j], a1);
        }
        f32x2 xx = *(const f32x2*)(x1 + (size_t)i * MV + m0);
        f32x2 oo; oo.x = g * a0 + xx.x; oo.y = g * a1 + xx.y;
        *(f32x2*)(out + (size_t)i * MV + m0) = oo;
    }
}

// ---------------------------------------------------------------------------
extern "C" void kernel_launch(void* const* d_in, const int* in_sizes, int n_in,
                              void* d_out, int out_size, void* d_ws, size_t ws_size,
                              hipStream_t stream)
{
    const float* x0    = (const float*)d_in[0];
    const float* x1    = (const float*)d_in[1];
    const float* Wq    = (const float*)d_in[2];
    const float* bq    = (const float*)d_in[3];
    const float* Wk    = (const float*)d_in[4];
    const float* bk    = (const float*)d_in[5];
    const float* Wv    = (const float*)d_in[6];
    const float* bv    = (const float*)d_in[7];
    const float* gamma = (const float*)d_in[8];

    float* ws     = (float*)d_ws;
    float* q      = ws;                                  // 8,388,608 f
    float* k      = q + (size_t)NB * NCQ * WHT;          // 8,388,608 f
    float* energy = k + (size_t)NB * NCQ * WHT;          //     1,024 f
    float* att    = energy + 1024;                       //     1,024 f

    ushort_t* wv_hi = (ushort_t*)(att + 1024);           // 65,536 us (16B-aligned)
    ushort_t* wq_hi = wv_hi + 65536;
    ushort_t* wq_lo = wq_hi + 16384;
    ushort_t* wk_hi = wq_lo + 16384;
    ushort_t* wk_lo = wk_hi + 16384;
    ushort_t* vbf   = wk_lo + 16384;                     // 33,554,432 us

    float* out     = (float*)d_out;
    float* att_out = out + (size_t)NB * NC * WHT;

    hipMemsetAsync(energy, 0, 1024 * sizeof(float), stream);

    prep_w<<<384, 256, 0, stream>>>(Wq, Wk, Wv, wv_hi, wq_hi, wq_lo, wk_hi, wk_lo);
    qkv_mfma<<<3072, 256, 0, stream>>>(x0, x1, wv_hi, wq_hi, wq_lo, wk_hi, wk_lo,
                                       bq, bk, bv, q, k, vbf);
    energy_kernel<<<dim3(1024, 2, 2), 256, 0, stream>>>(q, k, energy);
    softmax_kernel<<<1, 1024, 0, stream>>>(energy, att, att_out);
    out_kernel<<<2048, 256, 0, stream>>>(vbf, att, x1, gamma, out);
}

// Round 4
// 277.469 us; speedup vs baseline: 4.1051x; 1.0060x over previous
//
#include <hip/hip_runtime.h>

#define NB  32
#define NC  256
#define NCQ 64
#define WHT 4096                  // 64*64 spatial
#define DQK ((size_t)NCQ * WHT)   // 262144
#define MV  ((size_t)NC * WHT)    // 1048576

typedef __attribute__((ext_vector_type(8))) short short8;
typedef __attribute__((ext_vector_type(4))) float f32x4;
typedef __attribute__((ext_vector_type(2))) float f32x2;
typedef unsigned short ushort_t;

__device__ __forceinline__ ushort_t bf16_rne(float f) {
    union { float f; unsigned u; } v; v.f = f;
    unsigned r = (v.u + 0x7fffu + ((v.u >> 16) & 1u)) >> 16;
    return (ushort_t)r;
}
__device__ __forceinline__ float bf16_f(ushort_t h) {
    union { unsigned u; float f; } v; v.u = ((unsigned)h) << 16; return v.f;
}

// fragment-order offset within one 64x256 W tile (elements):
// value W[r][kk] lands at (kb=kk>>5)*2048 + lh*512 + m*128 + ll*8 + e
__device__ __forceinline__ int frag_off(int r, int kk) {
    return ((kk >> 5) * 16 + ((kk >> 3) & 3) * 4 + (r >> 4)) * 128
           + (r & 15) * 8 + (kk & 7);
}

// ---------------------------------------------------------------------------
// P: convert weights to bf16 hi (+lo for q/k), permuted to MFMA fragment order
// ---------------------------------------------------------------------------
__global__ __launch_bounds__(256)
void prep_w(const float* __restrict__ Wq, const float* __restrict__ Wk,
            const float* __restrict__ Wv,
            ushort_t* __restrict__ wv_hi,
            ushort_t* __restrict__ wq_hi, ushort_t* __restrict__ wq_lo,
            ushort_t* __restrict__ wk_hi, ushort_t* __restrict__ wk_lo)
{
    int i = blockIdx.x * 256 + threadIdx.x;
    if (i < 65536) {                       // Wv: 256 rows -> 4 tiles of 64
        int R = i >> 8, kk = i & 255;
        wv_hi[(R >> 6) * 16384 + frag_off(R & 63, kk)] = bf16_rne(Wv[i]);
    } else if (i < 81920) {                // Wq: 64 rows
        int j = i - 65536; int r = j >> 8, kk = j & 255;
        float f = Wq[j]; ushort_t h = bf16_rne(f);
        int o = frag_off(r, kk);
        wq_hi[o] = h; wq_lo[o] = bf16_rne(f - bf16_f(h));
    } else if (i < 98304) {                // Wk: 64 rows
        int j = i - 81920; int r = j >> 8, kk = j & 255;
        float f = Wk[j]; ushort_t h = bf16_rne(f);
        int o = frag_off(r, kk);
        wk_hi[o] = h; wk_lo[o] = bf16_rne(f - bf16_f(h));
    }
}

// ---------------------------------------------------------------------------
// K1: q/k/v projections, all-register MFMA (no LDS, no barriers).
// Per wave: 64 W-rows x 64 spatial. Block = 4 waves = 64 x 256 spatial.
// B-fragments loaded per-lane from x (dword, stride WHT); A-fragments from
// pre-permuted bf16 W (contiguous 16B). hi = trunc-top16 via v_perm; q/k use
// 3-pass hi/lo split MFMA; v is hi-only and stored bf16.
// ---------------------------------------------------------------------------
__global__ __launch_bounds__(256)
void qkv_mfma(const float* __restrict__ x0, const float* __restrict__ x1,
              const ushort_t* __restrict__ wv_hi,
              const ushort_t* __restrict__ wq_hi, const ushort_t* __restrict__ wq_lo,
              const ushort_t* __restrict__ wk_hi, const ushort_t* __restrict__ wk_lo,
              const float* __restrict__ bq, const float* __restrict__ bk,
              const float* __restrict__ bv,
              float* __restrict__ q, float* __restrict__ k,
              ushort_t* __restrict__ vbf)
{
    const int t   = threadIdx.x;
    const int bid = blockIdx.x;
    // bid -> (b, nt, mt): all 6 mt of one (b,nt) panel on one XCD (bid%8)
    const int xcd = bid & 7;
    const int sl  = bid >> 3;            // 0..383
    const int mt  = sl % 6;
    const int g   = (sl / 6) * 8 + xcd;  // 0..511
    const int nt  = g & 15;
    const int b   = g >> 4;

    const bool isV = (mt < 4);
    const bool isQ = (mt == 4);

    const int wave = t >> 6;
    const int lane = t & 63;
    const int lh   = lane >> 4;          // k-subchunk selector (0..3)
    const int ll   = lane & 15;

    const float* xsrc = ((mt == 5) ? x1 : x0) + (size_t)b * NC * WHT
                        + nt * 256 + wave * 64 + ll;
    const float* xw = xsrc + (size_t)lh * 8 * WHT;

    const ushort_t* whi = isV ? (wv_hi + mt * 16384) : (isQ ? wq_hi : wk_hi);
    const ushort_t* wlo = isQ ? wq_lo : wk_lo;
    const int abase = lh * 512 + ll * 8;

    f32x4 acc[4][4];
#pragma unroll
    for (int m = 0; m < 4; ++m)
#pragma unroll
        for (int n = 0; n < 4; ++n) acc[m][n] = (f32x4){0.f, 0.f, 0.f, 0.f};

    for (int kb = 0; kb < 8; ++kb) {
        // ---- A fragments (contiguous 16B, L2-hot) ----
        short8 a_hi[4], a_lo[4];
#pragma unroll
        for (int m = 0; m < 4; ++m)
            a_hi[m] = *(const short8*)(whi + kb * 2048 + abase + m * 128);
        if (!isV) {
#pragma unroll
            for (int m = 0; m < 4; ++m)
                a_lo[m] = *(const short8*)(wlo + kb * 2048 + abase + m * 128);
        }

        // ---- B: 32 per-lane dword loads ----
        const float* xk = xw + (size_t)kb * 32 * WHT;
        float xf[4][8];
#pragma unroll
        for (int n = 0; n < 4; ++n)
#pragma unroll
            for (int e = 0; e < 8; ++e)
                xf[n][e] = xk[(size_t)e * WHT + n * 16];

        // ---- hi = top16 truncation, packed 2-at-a-time via v_perm ----
        short8 bh[4];
#pragma unroll
        for (int n = 0; n < 4; ++n) {
            union { unsigned u[4]; short8 s; } pk;
#pragma unroll
            for (int p = 0; p < 4; ++p)
                pk.u[p] = __builtin_amdgcn_perm(
                    __float_as_uint(xf[n][2 * p + 1]),
                    __float_as_uint(xf[n][2 * p]), 0x07060302u);
            bh[n] = pk.s;
        }

        if (isV) {
#pragma unroll
            for (int n = 0; n < 4; ++n)
#pragma unroll
                for (int m = 0; m < 4; ++m)
                    acc[m][n] = __builtin_amdgcn_mfma_f32_16x16x32_bf16(
                        a_hi[m], bh[n], acc[m][n], 0, 0, 0);
        } else {
            short8 bl[4];
#pragma unroll
            for (int n = 0; n < 4; ++n) {
                float lo[8];
#pragma unroll
                for (int e = 0; e < 8; ++e) {
                    float hf = __uint_as_float(__float_as_uint(xf[n][e]) & 0xffff0000u);
                    lo[e] = xf[n][e] - hf;
                }
                union { unsigned u[4]; short8 s; } pk;
#pragma unroll
                for (int p = 0; p < 4; ++p)
                    pk.u[p] = __builtin_amdgcn_perm(
                        __float_as_uint(lo[2 * p + 1]),
                        __float_as_uint(lo[2 * p]), 0x07060302u);
                bl[n] = pk.s;
            }
#pragma unroll
            for (int n = 0; n < 4; ++n)
#pragma unroll
                for (int m = 0; m < 4; ++m) {
                    acc[m][n] = __builtin_amdgcn_mfma_f32_16x16x32_bf16(
                        a_hi[m], bh[n], acc[m][n], 0, 0, 0);
                    acc[m][n] = __builtin_amdgcn_mfma_f32_16x16x32_bf16(
                        a_hi[m], bl[n], acc[m][n], 0, 0, 0);
                    acc[m][n] = __builtin_amdgcn_mfma_f32_16x16x32_bf16(
                        a_lo[m], bh[n], acc[m][n], 0, 0, 0);
                }
        }
    }

    // ---- epilogue ----
    const int colbase = nt * 256 + wave * 64;
    if (isV) {
        ushort_t* outp = vbf + ((size_t)b * NC + mt * 64) * WHT + colbase;
        const float* bias = bv + mt * 64;
#pragma unroll
        for (int m = 0; m < 4; ++m)
#pragma unroll
            for (int n = 0; n < 4; ++n)
#pragma unroll
                for (int r = 0; r < 4; ++r) {
                    const int row = m * 16 + 4 * lh + r;
                    outp[(size_t)row * WHT + n * 16 + ll] =
                        bf16_rne(acc[m][n][r] + bias[row]);
                }
    } else {
        float* outp = (isQ ? q : k) + (size_t)b * NCQ * WHT + colbase;
        const float* bias = isQ ? bq : bk;
#pragma unroll
        for (int m = 0; m < 4; ++m)
#pragma unroll
            for (int n = 0; n < 4; ++n)
#pragma unroll
                for (int r = 0; r < 4; ++r) {
                    const int row = m * 16 + 4 * lh + r;
                    outp[(size_t)row * WHT + n * 16 + ll] =
                        acc[m][n][r] + bias[row];
                }
    }
}

// ---------------------------------------------------------------------------
// K2: energy[i,j] = sum_d k[i,d]*q[j,d]  (32x32, K=262144) — unchanged
// ---------------------------------------------------------------------------
__global__ __launch_bounds__(256)
void energy_kernel(const float* __restrict__ q, const float* __restrict__ k,
                   float* __restrict__ energy)
{
    __shared__ float kt[256][17];
    __shared__ float qt[256][17];

    const int t  = threadIdx.x;
    const int d0 = blockIdx.x * 256;
    const int ih = blockIdx.y;
    const int jh = blockIdx.z;

    for (int r = 0; r < 16; ++r) {
        kt[t][r] = k[(size_t)(ih * 16 + r) * DQK + d0 + t];
        qt[t][r] = q[(size_t)(jh * 16 + r) * DQK + d0 + t];
    }
    __syncthreads();

    const int ii = t >> 4;
    const int jj = t & 15;
    float acc = 0.f;
#pragma unroll 4
    for (int d = 0; d < 256; ++d)
        acc = fmaf(kt[d][ii], qt[d][jj], acc);

    atomicAdd(&energy[(ih * 16 + ii) * 32 + jh * 16 + jj], acc);
}

// ---------------------------------------------------------------------------
// K2b: row softmax of energy [32x32]. 1 block, 1024 threads. — unchanged
// ---------------------------------------------------------------------------
__global__ __launch_bounds__(1024)
void softmax_kernel(const float* __restrict__ energy,
                    float* __restrict__ att, float* __restrict__ att_out)
{
    const int t = threadIdx.x;
    const int i = t >> 5;
    const int j = t & 31;
    float e = energy[i * 32 + j];
    float m = e;
#pragma unroll
    for (int o = 16; o; o >>= 1) m = fmaxf(m, __shfl_xor(m, o, 32));
    float ex = __expf(e - m);
    float s = ex;
#pragma unroll
    for (int o = 16; o; o >>= 1) s += __shfl_xor(s, o, 32);
    float a = ex / s;
    att[i * 32 + j] = a;
    att_out[i * 32 + j] = a;
}

// ---------------------------------------------------------------------------
// K3: out[i,m] = gamma * sum_j A[i,j]*v[j,m] + x1[i,m]; v is bf16-packed.
// 2 spatial positions per thread (uint v loads, float2 x1/out).
// ---------------------------------------------------------------------------
__global__ __launch_bounds__(256)
void out_kernel(const ushort_t* __restrict__ vbf, const float* __restrict__ att,
                const float* __restrict__ x1, const float* __restrict__ gamma,
                float* __restrict__ out)
{
    const int t = threadIdx.x;
    const size_t m0 = (size_t)blockIdx.x * 512 + 2 * t;

    float v0[32], v1[32];
#pragma unroll
    for (int j = 0; j < 32; ++j) {
        unsigned u = *(const unsigned*)(vbf + (size_t)j * MV + m0);
        v0[j] = __uint_as_float(u << 16);
        v1[j] = __uint_as_float(u & 0xffff0000u);
    }

    const float g = gamma[0];
    for (int i = 0; i < 32; ++i) {
        float a0 = 0.f, a1 = 0.f;
#pragma unroll
        for (int j = 0; j < 32; ++j) {
            float w = att[i * 32 + j];
            a0 = fmaf(w, v0[j], a0);
            a1 = fmaf(w, v1[j], a1);
        }
        f32x2 xx = *(const f32x2*)(x1 + (size_t)i * MV + m0);
        f32x2 oo; oo.x = g * a0 + xx.x; oo.y = g * a1 + xx.y;
        *(f32x2*)(out + (size_t)i * MV + m0) = oo;
    }
}

// ---------------------------------------------------------------------------
extern "C" void kernel_launch(void* const* d_in, const int* in_sizes, int n_in,
                              void* d_out, int out_size, void* d_ws, size_t ws_size,
                              hipStream_t stream)
{
    const float* x0    = (const float*)d_in[0];
    const float* x1    = (const float*)d_in[1];
    const float* Wq    = (const float*)d_in[2];
    const float* bq    = (const float*)d_in[3];
    const float* Wk    = (const float*)d_in[4];
    const float* bk    = (const float*)d_in[5];
    const float* Wv    = (const float*)d_in[6];
    const float* bv    = (const float*)d_in[7];
    const float* gamma = (const float*)d_in[8];

    float* ws     = (float*)d_ws;
    float* q      = ws;                                  // 8,388,608 f
    float* k      = q + (size_t)NB * NCQ * WHT;          // 8,388,608 f
    float* energy = k + (size_t)NB * NCQ * WHT;          //     1,024 f
    float* att    = energy + 1024;                       //     1,024 f

    ushort_t* wv_hi = (ushort_t*)(att + 1024);           // 65,536 us (16B-aligned)
    ushort_t* wq_hi = wv_hi + 65536;
    ushort_t* wq_lo = wq_hi + 16384;
    ushort_t* wk_hi = wq_lo + 16384;
    ushort_t* wk_lo = wk_hi + 16384;
    ushort_t* vbf   = wk_lo + 16384;                     // 33,554,432 us

    float* out     = (float*)d_out;
    float* att_out = out + (size_t)NB * NC * WHT;

    hipMemsetAsync(energy, 0, 1024 * sizeof(float), stream);

    prep_w<<<384, 256, 0, stream>>>(Wq, Wk, Wv, wv_hi, wq_hi, wq_lo, wk_hi, wk_lo);
    qkv_mfma<<<3072, 256, 0, stream>>>(x0, x1, wv_hi, wq_hi, wq_lo, wk_hi, wk_lo,
                                       bq, bk, bv, q, k, vbf);
    energy_kernel<<<dim3(1024, 2, 2), 256, 0, stream>>>(q, k, energy);
    softmax_kernel<<<1, 1024, 0, stream>>>(energy, att, att_out);
    out_kernel<<<2048, 256, 0, stream>>>(vbf, att, x1, gamma, out);
}

// Round 5
// 246.044 us; speedup vs baseline: 4.6293x; 1.1277x over previous
//
#include <hip/hip_runtime.h>

#define NB  32
#define NC  256
#define NCQ 64
#define WHT 4096                  // 64*64 spatial
#define DQK ((size_t)NCQ * WHT)   // 262144
#define MV  ((size_t)NC * WHT)    // 1048576

typedef __attribute__((ext_vector_type(8))) short short8;
typedef __attribute__((ext_vector_type(4))) float f32x4;
typedef __attribute__((ext_vector_type(2))) float f32x2;
typedef unsigned short ushort_t;

__device__ __forceinline__ ushort_t bf16_rne(float f) {
    union { float f; unsigned u; } v; v.f = f;
    unsigned r = (v.u + 0x7fffu + ((v.u >> 16) & 1u)) >> 16;
    return (ushort_t)r;
}
__device__ __forceinline__ float bf16_f(ushort_t h) {
    union { unsigned u; float f; } v; v.u = ((unsigned)h) << 16; return v.f;
}

// fragment-order offset within one 64x256 W tile (elements):
// value W[r][kk] lands at (kb=kk>>5)*2048 + lh*512 + m*128 + ll*8 + e
__device__ __forceinline__ int frag_off(int r, int kk) {
    return ((kk >> 5) * 16 + ((kk >> 3) & 3) * 4 + (r >> 4)) * 128
           + (r & 15) * 8 + (kk & 7);
}

// ---------------------------------------------------------------------------
// P: convert weights to bf16 hi (+lo for q/k), permuted to MFMA fragment order
// ---------------------------------------------------------------------------
__global__ __launch_bounds__(256)
void prep_w(const float* __restrict__ Wq, const float* __restrict__ Wk,
            const float* __restrict__ Wv,
            ushort_t* __restrict__ wv_hi,
            ushort_t* __restrict__ wq_hi, ushort_t* __restrict__ wq_lo,
            ushort_t* __restrict__ wk_hi, ushort_t* __restrict__ wk_lo)
{
    int i = blockIdx.x * 256 + threadIdx.x;
    if (i < 65536) {                       // Wv: 256 rows -> 4 tiles of 64
        int R = i >> 8, kk = i & 255;
        wv_hi[(R >> 6) * 16384 + frag_off(R & 63, kk)] = bf16_rne(Wv[i]);
    } else if (i < 81920) {                // Wq: 64 rows
        int j = i - 65536; int r = j >> 8, kk = j & 255;
        float f = Wq[j]; ushort_t h = bf16_rne(f);
        int o = frag_off(r, kk);
        wq_hi[o] = h; wq_lo[o] = bf16_rne(f - bf16_f(h));
    } else if (i < 98304) {                // Wk: 64 rows
        int j = i - 81920; int r = j >> 8, kk = j & 255;
        float f = Wk[j]; ushort_t h = bf16_rne(f);
        int o = frag_off(r, kk);
        wk_hi[o] = h; wk_lo[o] = bf16_rne(f - bf16_f(h));
    }
}

// load next-kb B tile (2 n-groups x 8 k-elems) into register buffer
#define LOADB(dst, kbv) do {                                            \
    const float* xk_ = xw + (size_t)(kbv) * 32 * WHT;                   \
    _Pragma("unroll") for (int n_ = 0; n_ < 2; ++n_)                    \
    _Pragma("unroll") for (int e_ = 0; e_ < 8; ++e_)                    \
        dst[n_][e_] = xk_[(size_t)e_ * WHT + n_ * 16];                  \
} while (0)

// ---------------------------------------------------------------------------
// K1: q/k/v projections via bf16 MFMA.
// Block = 512 threads = 8 waves; block tile 64 rows x 256 spatial; per-wave
// tile 64x32 (acc[4][2], 32 VGPR) -> prefetch fits under 128-VGPR bracket.
// W fragments staged to LDS once per block (one barrier, conflict-free
// b128 reads). B (x) loads register-double-buffered across the unrolled
// kb loop. q/k: 3-pass hi/lo split; v: hi-only, stored bf16.
// ---------------------------------------------------------------------------
__global__ __launch_bounds__(512, 4)
void qkv_mfma(const float* __restrict__ x0, const float* __restrict__ x1,
              const ushort_t* __restrict__ wv_hi,
              const ushort_t* __restrict__ wq_hi, const ushort_t* __restrict__ wq_lo,
              const ushort_t* __restrict__ wk_hi, const ushort_t* __restrict__ wk_lo,
              const float* __restrict__ bq, const float* __restrict__ bk,
              const float* __restrict__ bv,
              float* __restrict__ q, float* __restrict__ k,
              ushort_t* __restrict__ vbf)
{
    __shared__ ushort_t lds_hi[16384];   // 32 KB, fragment order
    __shared__ ushort_t lds_lo[16384];   // 32 KB (qk blocks only)

    const int t   = threadIdx.x;
    const int bid = blockIdx.x;
    // bid -> (b, nt, mt): all 6 mt of one (b,nt) panel on one XCD (bid%8)
    const int xcd = bid & 7;
    const int sl  = bid >> 3;            // 0..383
    const int mt  = sl % 6;
    const int g   = (sl / 6) * 8 + xcd;  // 0..511
    const int nt  = g & 15;
    const int b   = g >> 4;

    const bool isV = (mt < 4);
    const bool isQ = (mt == 4);

    const int wave = t >> 6;
    const int lane = t & 63;
    const int lh   = lane >> 4;          // k-subchunk selector (0..3)
    const int ll   = lane & 15;

    const ushort_t* whi = isV ? (wv_hi + mt * 16384) : (isQ ? wq_hi : wk_hi);
    const ushort_t* wlo = isQ ? wq_lo : wk_lo;

    // ---- stage W tile(s) to LDS (linear fragment-order copy) ----
#pragma unroll
    for (int r = 0; r < 4; ++r)
        *(short8*)&lds_hi[(r * 512 + t) * 8] = *(const short8*)(whi + (r * 512 + t) * 8);
    if (!isV) {
#pragma unroll
        for (int r = 0; r < 4; ++r)
            *(short8*)&lds_lo[(r * 512 + t) * 8] = *(const short8*)(wlo + (r * 512 + t) * 8);
    }
    __syncthreads();

    const float* xw = ((mt == 5) ? x1 : x0) + (size_t)b * NC * WHT
                      + nt * 256 + wave * 32 + ll + (size_t)lh * 8 * WHT;
    const int abase = lh * 512 + ll * 8;

    f32x4 acc[4][2];
#pragma unroll
    for (int m = 0; m < 4; ++m)
#pragma unroll
        for (int n = 0; n < 2; ++n) acc[m][n] = (f32x4){0.f, 0.f, 0.f, 0.f};

    float xfA[2][8], xfB[2][8];
    LOADB(xfA, 0);

#pragma unroll
    for (int kb = 0; kb < 8; ++kb) {
        float (*cur)[8] = (kb & 1) ? xfB : xfA;
        float (*nxt)[8] = (kb & 1) ? xfA : xfB;
        if (kb < 7) LOADB(nxt, kb + 1);

        // ---- hi = top16 truncation, packed via v_perm ----
        short8 bh[2];
#pragma unroll
        for (int n = 0; n < 2; ++n) {
            union { unsigned u[4]; short8 s; } pk;
#pragma unroll
            for (int p = 0; p < 4; ++p)
                pk.u[p] = __builtin_amdgcn_perm(
                    __float_as_uint(cur[n][2 * p + 1]),
                    __float_as_uint(cur[n][2 * p]), 0x07060302u);
            bh[n] = pk.s;
        }

        if (isV) {
#pragma unroll
            for (int m = 0; m < 4; ++m) {
                short8 a_hi = *(const short8*)&lds_hi[kb * 2048 + abase + m * 128];
#pragma unroll
                for (int n = 0; n < 2; ++n)
                    acc[m][n] = __builtin_amdgcn_mfma_f32_16x16x32_bf16(
                        a_hi, bh[n], acc[m][n], 0, 0, 0);
            }
        } else {
            short8 bl[2];
#pragma unroll
            for (int n = 0; n < 2; ++n) {
                float lo[8];
#pragma unroll
                for (int e = 0; e < 8; ++e) {
                    float hf = __uint_as_float(__float_as_uint(cur[n][e]) & 0xffff0000u);
                    lo[e] = cur[n][e] - hf;
                }
                union { unsigned u[4]; short8 s; } pk;
#pragma unroll
                for (int p = 0; p < 4; ++p)
                    pk.u[p] = __builtin_amdgcn_perm(
                        __float_as_uint(lo[2 * p + 1]),
                        __float_as_uint(lo[2 * p]), 0x07060302u);
                bl[n] = pk.s;
            }
#pragma unroll
            for (int m = 0; m < 4; ++m) {
                short8 a_hi = *(const short8*)&lds_hi[kb * 2048 + abase + m * 128];
                short8 a_lo = *(const short8*)&lds_lo[kb * 2048 + abase + m * 128];
#pragma unroll
                for (int n = 0; n < 2; ++n) {
                    acc[m][n] = __builtin_amdgcn_mfma_f32_16x16x32_bf16(
                        a_hi, bh[n], acc[m][n], 0, 0, 0);
                    acc[m][n] = __builtin_amdgcn_mfma_f32_16x16x32_bf16(
                        a_hi, bl[n], acc[m][n], 0, 0, 0);
                    acc[m][n] = __builtin_amdgcn_mfma_f32_16x16x32_bf16(
                        a_lo, bh[n], acc[m][n], 0, 0, 0);
                }
            }
        }
    }

    // ---- epilogue ----
    const int colbase = nt * 256 + wave * 32;
    if (isV) {
        ushort_t* outp = vbf + ((size_t)b * NC + mt * 64) * WHT + colbase;
        const float* bias = bv + mt * 64;
#pragma unroll
        for (int m = 0; m < 4; ++m)
#pragma unroll
            for (int n = 0; n < 2; ++n)
#pragma unroll
                for (int r = 0; r < 4; ++r) {
                    const int row = m * 16 + 4 * lh + r;
                    outp[(size_t)row * WHT + n * 16 + ll] =
                        bf16_rne(acc[m][n][r] + bias[row]);
                }
    } else {
        float* outp = (isQ ? q : k) + (size_t)b * NCQ * WHT + colbase;
        const float* bias = isQ ? bq : bk;
#pragma unroll
        for (int m = 0; m < 4; ++m)
#pragma unroll
            for (int n = 0; n < 2; ++n)
#pragma unroll
                for (int r = 0; r < 4; ++r) {
                    const int row = m * 16 + 4 * lh + r;
                    outp[(size_t)row * WHT + n * 16 + ll] =
                        acc[m][n][r] + bias[row];
                }
    }
}

// ---------------------------------------------------------------------------
// K2: energy[i,j] = sum_d k[i,d]*q[j,d]  (32x32, K=262144)
// 4 independent accumulators to break the serial FMA chain.
// ---------------------------------------------------------------------------
__global__ __launch_bounds__(256)
void energy_kernel(const float* __restrict__ q, const float* __restrict__ k,
                   float* __restrict__ energy)
{
    __shared__ float kt[256][17];
    __shared__ float qt[256][17];

    const int t  = threadIdx.x;
    const int d0 = blockIdx.x * 256;
    const int ih = blockIdx.y;
    const int jh = blockIdx.z;

    for (int r = 0; r < 16; ++r) {
        kt[t][r] = k[(size_t)(ih * 16 + r) * DQK + d0 + t];
        qt[t][r] = q[(size_t)(jh * 16 + r) * DQK + d0 + t];
    }
    __syncthreads();

    const int ii = t >> 4;
    const int jj = t & 15;
    float a0 = 0.f, a1 = 0.f, a2 = 0.f, a3 = 0.f;
#pragma unroll 8
    for (int d = 0; d < 256; d += 4) {
        a0 = fmaf(kt[d + 0][ii], qt[d + 0][jj], a0);
        a1 = fmaf(kt[d + 1][ii], qt[d + 1][jj], a1);
        a2 = fmaf(kt[d + 2][ii], qt[d + 2][jj], a2);
        a3 = fmaf(kt[d + 3][ii], qt[d + 3][jj], a3);
    }

    atomicAdd(&energy[(ih * 16 + ii) * 32 + jh * 16 + jj], (a0 + a1) + (a2 + a3));
}

// ---------------------------------------------------------------------------
// K2b: row softmax of energy [32x32]. 1 block, 1024 threads. — unchanged
// ---------------------------------------------------------------------------
__global__ __launch_bounds__(1024)
void softmax_kernel(const float* __restrict__ energy,
                    float* __restrict__ att, float* __restrict__ att_out)
{
    const int t = threadIdx.x;
    const int i = t >> 5;
    const int j = t & 31;
    float e = energy[i * 32 + j];
    float m = e;
#pragma unroll
    for (int o = 16; o; o >>= 1) m = fmaxf(m, __shfl_xor(m, o, 32));
    float ex = __expf(e - m);
    float s = ex;
#pragma unroll
    for (int o = 16; o; o >>= 1) s += __shfl_xor(s, o, 32);
    float a = ex / s;
    att[i * 32 + j] = a;
    att_out[i * 32 + j] = a;
}

// ---------------------------------------------------------------------------
// K3: out[i,m] = gamma * sum_j A[i,j]*v[j,m] + x1[i,m]; v is bf16-packed.
// ---------------------------------------------------------------------------
__global__ __launch_bounds__(256)
void out_kernel(const ushort_t* __restrict__ vbf, const float* __restrict__ att,
                const float* __restrict__ x1, const float* __restrict__ gamma,
                float* __restrict__ out)
{
    const int t = threadIdx.x;
    const size_t m0 = (size_t)blockIdx.x * 512 + 2 * t;

    float v0[32], v1[32];
#pragma unroll
    for (int j = 0; j < 32; ++j) {
        unsigned u = *(const unsigned*)(vbf + (size_t)j * MV + m0);
        v0[j] = __uint_as_float(u << 16);
        v1[j] = __uint_as_float(u & 0xffff0000u);
    }

    const float g = gamma[0];
    for (int i = 0; i < 32; ++i) {
        float a0 = 0.f, a1 = 0.f;
#pragma unroll
        for (int j = 0; j < 32; ++j) {
            float w = att[i * 32 + j];
            a0 = fmaf(w, v0[j], a0);
            a1 = fmaf(w, v1[j], a1);
        }
        f32x2 xx = *(const f32x2*)(x1 + (size_t)i * MV + m0);
        f32x2 oo; oo.x = g * a0 + xx.x; oo.y = g * a1 + xx.y;
        *(f32x2*)(out + (size_t)i * MV + m0) = oo;
    }
}

// ---------------------------------------------------------------------------
extern "C" void kernel_launch(void* const* d_in, const int* in_sizes, int n_in,
                              void* d_out, int out_size, void* d_ws, size_t ws_size,
                              hipStream_t stream)
{
    const float* x0    = (const float*)d_in[0];
    const float* x1    = (const float*)d_in[1];
    const float* Wq    = (const float*)d_in[2];
    const float* bq    = (const float*)d_in[3];
    const float* Wk    = (const float*)d_in[4];
    const float* bk    = (const float*)d_in[5];
    const float* Wv    = (const float*)d_in[6];
    const float* bv    = (const float*)d_in[7];
    const float* gamma = (const float*)d_in[8];

    float* ws     = (float*)d_ws;
    float* q      = ws;                                  // 8,388,608 f
    float* k      = q + (size_t)NB * NCQ * WHT;          // 8,388,608 f
    float* energy = k + (size_t)NB * NCQ * WHT;          //     1,024 f
    float* att    = energy + 1024;                       //     1,024 f

    ushort_t* wv_hi = (ushort_t*)(att + 1024);           // 65,536 us (16B-aligned)
    ushort_t* wq_hi = wv_hi + 65536;
    ushort_t* wq_lo = wq_hi + 16384;
    ushort_t* wk_hi = wq_lo + 16384;
    ushort_t* wk_lo = wk_hi + 16384;
    ushort_t* vbf   = wk_lo + 16384;                     // 33,554,432 us

    float* out     = (float*)d_out;
    float* att_out = out + (size_t)NB * NC * WHT;

    hipMemsetAsync(energy, 0, 1024 * sizeof(float), stream);

    prep_w<<<384, 256, 0, stream>>>(Wq, Wk, Wv, wv_hi, wq_hi, wq_lo, wk_hi, wk_lo);
    qkv_mfma<<<3072, 512, 0, stream>>>(x0, x1, wv_hi, wq_hi, wq_lo, wk_hi, wk_lo,
                                       bq, bk, bv, q, k, vbf);
    energy_kernel<<<dim3(1024, 2, 2), 256, 0, stream>>>(q, k, energy);
    softmax_kernel<<<1, 1024, 0, stream>>>(energy, att, att_out);
    out_kernel<<<2048, 256, 0, stream>>>(vbf, att, x1, gamma, out);
}